// Round 5
// baseline (111.345 us; speedup 1.0000x reference)
//
#include <hip/hip_runtime.h>
#include <math.h>

#define NT     128
#define NB     16
#define NH     512
#define SEQ_L  1024
#define FFT_N  2048
#define RS     0.70710678118654752f
#define C16    0.92387953251128675f   // cos(pi/8)
#define S16    0.38268343236508977f   // sin(pi/8)

// Complex as a 2-wide fp32 ext-vector so the compiler emits packed VOP3P
// (v_pk_add_f32 / v_pk_mul_f32 / v_pk_fma_f32): 2 fp32 ops per instruction.
typedef float f2 __attribute__((ext_vector_type(2)));

__device__ __forceinline__ f2 in_(f2 v) { return (f2){v.y, -v.x}; }   // -i*v
__device__ __forceinline__ f2 ip_(f2 v) { return (f2){-v.y, v.x}; }   // +i*v
__device__ __forceinline__ f2 cmul(f2 a, f2 b) {                      // a*b
    return a.x * b + a.y * (f2){-b.y, b.x};
}
__device__ __forceinline__ f2 cmulj(f2 a, f2 b) {                     // a*conj(b)
    return b.x * a + b.y * (f2){a.y, -a.x};
}

// float2-granular padded LDS: Q(x) = x + (x>>4); folded affine bases ->
// one base VGPR + compile-time immediate per DS op; <=2-way bank aliasing.
#define BUF2_SZ 2176   // Q(2047) = 2174

// K in stage-permuted, conv-lane-coalesced order: [h][(4*gi+q)*128 + t] float4.
__device__ __align__(16) float4 g_kf4[(size_t)NH * (FFT_N / 2)];

// In-place DFT4, natural order. SIGN=-1 fwd, SIGN=+1 inverse.
template <int SIGN>
__device__ __forceinline__ void dft4(f2 x[4]) {
    f2 s0 = x[0] + x[2], s1 = x[0] - x[2];
    f2 s2 = x[1] + x[3], s3 = x[1] - x[3];
    x[0] = s0 + s2;
    x[2] = s0 - s2;
    if (SIGN < 0) { x[1] = s1 + in_(s3); x[3] = s1 + ip_(s3); }
    else          { x[1] = s1 + ip_(s3); x[3] = s1 + in_(s3); }
}

// In-place DFT8, natural order.
template <int SIGN>
__device__ __forceinline__ void dft8(f2 x[8]) {
    f2 e0 = x[0] + x[4], e1 = x[1] + x[5];
    f2 e2 = x[2] + x[6], e3 = x[3] + x[7];
    f2 o0 = x[0] - x[4], o1 = x[1] - x[5];
    f2 o2 = x[2] - x[6], o3 = x[3] - x[7];
    f2 t1, t2, t3;
    if (SIGN < 0) {
        t1 = RS * (o1 + in_(o1));
        t2 = in_(o2);
        t3 = -RS * (o3 + ip_(o3));
    } else {
        t1 = RS * (o1 + ip_(o1));
        t2 = ip_(o2);
        t3 = -RS * (o3 + in_(o3));
    }
    f2 s0 = e0 + e2, s1 = e0 - e2, s2 = e1 + e3, s3 = e1 - e3;
    x[0] = s0 + s2;
    x[4] = s0 - s2;
    f2 u0 = o0 + t2, u1 = o0 - t2, u2 = t1 + t3, u3 = t1 - t3;
    x[1] = u0 + u2;
    x[5] = u0 - u2;
    if (SIGN < 0) {
        x[2] = s1 + in_(s3); x[6] = s1 + ip_(s3);
        x[3] = u1 + in_(u3); x[7] = u1 + ip_(u3);
    } else {
        x[2] = s1 + ip_(s3); x[6] = s1 + in_(s3);
        x[3] = u1 + ip_(u3); x[7] = u1 + in_(u3);
    }
}

// Internal W16 twiddles for the 4x4 CT decomposition of DFT16.
template <int SIGN>
__device__ __forceinline__ void dft16_twiddle(f2 v[4][4]) {
    const float sg = (SIGN < 0) ? -1.f : 1.f;
    const f2 W1 = (f2){C16, sg * S16};
    const f2 W2 = (f2){RS, sg * RS};
    const f2 W3 = (f2){S16, sg * C16};
    const f2 W6 = (f2){-RS, sg * RS};
    const f2 W9 = (f2){-C16, -sg * S16};
    v[1][1] = cmul(v[1][1], W1);
    v[1][2] = cmul(v[1][2], W2);
    v[1][3] = cmul(v[1][3], W3);
    v[2][1] = cmul(v[2][1], W2);
    v[2][2] = (SIGN < 0) ? in_(v[2][2]) : ip_(v[2][2]);   // *W16^4
    v[2][3] = cmul(v[2][3], W6);
    v[3][1] = cmul(v[3][1], W3);
    v[3][2] = cmul(v[3][2], W6);
    v[3][3] = cmul(v[3][3], W9);
}

// Full in-place DFT16, natural order.
template <int SIGN>
__device__ __forceinline__ void dft16(f2 x[16]) {
    f2 v[4][4];
#pragma unroll
    for (int n0 = 0; n0 < 4; ++n0) {
        f2 a[4] = {x[n0], x[n0 + 4], x[n0 + 8], x[n0 + 12]};
        dft4<SIGN>(a);
        v[n0][0] = a[0]; v[n0][1] = a[1]; v[n0][2] = a[2]; v[n0][3] = a[3];
    }
    dft16_twiddle<SIGN>(v);
#pragma unroll
    for (int k0 = 0; k0 < 4; ++k0) {
        f2 a[4] = {v[0][k0], v[1][k0], v[2][k0], v[3][k0]};
        dft4<SIGN>(a);
        x[k0] = a[0]; x[k0 + 4] = a[1]; x[k0 + 8] = a[2]; x[k0 + 12] = a[3];
    }
}

// Forward DFT16 with inputs 8..15 implicitly zero.
__device__ __forceinline__ void dft16_zero8(const f2 z[8], f2 x[16]) {
    f2 v[4][4];
#pragma unroll
    for (int n0 = 0; n0 < 4; ++n0) {
        f2 a = z[n0], b = z[n0 + 4];
        v[n0][0] = a + b;
        v[n0][1] = a + in_(b);
        v[n0][2] = a - b;
        v[n0][3] = a + ip_(b);
    }
    dft16_twiddle<-1>(v);
#pragma unroll
    for (int k0 = 0; k0 < 4; ++k0) {
        f2 a[4] = {v[0][k0], v[1][k0], v[2][k0], v[3][k0]};
        dft4<-1>(a);
        x[k0] = a[0]; x[k0 + 4] = a[1]; x[k0 + 8] = a[2]; x[k0 + 12] = a[3];
    }
}

// Inverse DFT16 computing only outputs 0..7.
__device__ __forceinline__ void dft16_inv_low8(const f2 x[16], f2 y[8]) {
    f2 v[4][4];
#pragma unroll
    for (int n0 = 0; n0 < 4; ++n0) {
        f2 a[4] = {x[n0], x[n0 + 4], x[n0 + 8], x[n0 + 12]};
        dft4<+1>(a);
        v[n0][0] = a[0]; v[n0][1] = a[1]; v[n0][2] = a[2]; v[n0][3] = a[3];
    }
    dft16_twiddle<+1>(v);
#pragma unroll
    for (int k0 = 0; k0 < 4; ++k0) {
        f2 x0 = v[0][k0], x1 = v[1][k0], x2 = v[2][k0], x3 = v[3][k0];
        f2 s0 = x0 + x2, s1 = x0 - x2;
        f2 s2 = x1 + x3, s3 = x1 - x3;
        y[k0]     = s0 + s2;            // k1 = 0
        y[k0 + 4] = s1 + ip_(s3);       // k1 = 1
    }
}

// Apply x[c] *= a^c (CONJ=0) or x[c] *= conj(a^c) (CONJ=1), c = 1..15.
// Log-depth power tree: pure VALU, zero memory latency.
template <int CONJ>
__device__ __forceinline__ void tw_apply16(f2 x[16], f2 a) {
#define AP(v, w) (v) = CONJ ? cmulj((v), (w)) : cmul((v), (w))
    AP(x[1], a);
    f2 w2 = cmul(a, a);      AP(x[2], w2);
    f2 w3 = cmul(w2, a);     AP(x[3], w3);
    f2 w4 = cmul(w2, w2);    AP(x[4], w4);
    f2 w5 = cmul(w4, a);     AP(x[5], w5);
    f2 w6 = cmul(w4, w2);    AP(x[6], w6);
    f2 w7 = cmul(w6, a);     AP(x[7], w7);
    f2 w8 = cmul(w4, w4);    AP(x[8], w8);
    f2 w9 = cmul(w8, a);     AP(x[9], w9);
    f2 w10 = cmul(w8, w2);   AP(x[10], w10);
    f2 w11 = cmul(w10, a);   AP(x[11], w11);
    f2 w12 = cmul(w8, w4);   AP(x[12], w12);
    f2 w13 = cmul(w12, a);   AP(x[13], w13);
    f2 w14 = cmul(w12, w2);  AP(x[14], w14);
    f2 w15 = cmul(w14, a);   AP(x[15], w15);
#undef AP
}

// ---- Kernel 1: K = fwd-chain(pad(k[h])) stored permuted+coalesced ----
__global__ __launch_bounds__(NT, 2) void kfft_kernel(const float* __restrict__ kin) {
    __shared__ f2 buf[BUF2_SZ];
    __shared__ f2 twlds[NT];
    const int t = threadIdx.x;
    const int h = blockIdx.x;
    f2 w1;
    {
        float sv, cv;
        sincosf(-6.283185307179586f * (float)t / (float)FFT_N, &sv, &cv);
        w1 = (f2){cv, sv};
        twlds[t] = w1;
    }
    const int pb1 = t + (t >> 4);          // Q(t + 128c) = pb1 + 136c
    const float* krow = kin + (size_t)h * SEQ_L;
    {
        f2 z[8], x[16];
#pragma unroll
        for (int j = 0; j < 8; ++j) z[j] = (f2){krow[t + 128 * j], 0.f};
        dft16_zero8(z, x);
        tw_apply16<0>(x, w1);
#pragma unroll
        for (int c = 0; c < 16; ++c) buf[pb1 + 136 * c] = x[c];
    }
    __syncthreads();
    const int cblk = t >> 3, r = t & 7;
    const int pb2 = 136 * cblk + r;        // Q(128cblk + r + 8j) = pb2 + 8j + (j>>1)
    {
        f2 x[16];
#pragma unroll
        for (int j = 0; j < 16; ++j) x[j] = buf[pb2 + 8 * j + (j >> 1)];
        dft16<-1>(x);
        tw_apply16<0>(x, twlds[16 * r]);
#pragma unroll
        for (int c2 = 0; c2 < 16; ++c2) buf[pb2 + 8 * c2 + (c2 >> 1)] = x[c2];
    }
    __syncthreads();
    const int pb3 = 17 * t;                // Q(16t + 8gi + l) = pb3 + 8gi + l
    float4* kf4 = g_kf4 + (size_t)h * (FFT_N / 2);
#pragma unroll
    for (int gi = 0; gi < 2; ++gi) {
        f2 x[8];
#pragma unroll
        for (int l = 0; l < 8; ++l) x[l] = buf[pb3 + 8 * gi + l];
        dft8<-1>(x);
#pragma unroll
        for (int q = 0; q < 4; ++q)
            kf4[(4 * gi + q) * 128 + t] =
                make_float4(x[2 * q].x, x[2 * q].y, x[2 * q + 1].x, x[2 * q + 1].y);
    }
}

// ---- Kernel 2: rows (2bp,h),(2bp+1,h) packed: fwd chain -> *K -> adjoint ----
// u is loaded ONCE (s1) and kept live in 8 f2 registers for the epilogue:
// cuts the second 33.5 MB u read (L2-evicted across the 4 phases) from HBM.
__global__ __launch_bounds__(NT, 2) void conv_pair_kernel(const float* __restrict__ u,
                                                          const float* __restrict__ D,
                                                          float* __restrict__ out) {
    __shared__ f2 buf[BUF2_SZ];
    __shared__ f2 twlds[NT];
    const int t = threadIdx.x;
    const int h = blockIdx.x & (NH - 1);
    const int bp = blockIdx.x >> 9;
    const size_t row0 = (size_t)(2 * bp) * NH + h;
    const size_t row1 = row0 + NH;
    const float* u0 = u + row0 * SEQ_L;
    const float* u1 = u + row1 * SEQ_L;
    f2 w1;
    {
        float sv, cv;
        sincosf(-6.283185307179586f * (float)t / (float)FFT_N, &sv, &cv);
        w1 = (f2){cv, sv};
        twlds[t] = w1;
    }
    const int pb1 = t + (t >> 4);
    f2 uz[8];   // (u0,u1) packed — stays live to the epilogue
    // s1 fwd (write-only into LDS)
    {
        f2 x[16];
#pragma unroll
        for (int j = 0; j < 8; ++j)
            uz[j] = (f2){u0[t + 128 * j], u1[t + 128 * j]};
        dft16_zero8(uz, x);
        tw_apply16<0>(x, w1);
#pragma unroll
        for (int c = 0; c < 16; ++c) buf[pb1 + 136 * c] = x[c];
    }
    __syncthreads();
    // s2 fwd (in-place)
    const int cblk = t >> 3, r = t & 7;
    const int pb2 = 136 * cblk + r;
    const f2 ws = twlds[16 * r];   // W_128^r
    {
        f2 x[16];
#pragma unroll
        for (int j = 0; j < 16; ++j) x[j] = buf[pb2 + 8 * j + (j >> 1)];
        dft16<-1>(x);
        tw_apply16<0>(x, ws);
#pragma unroll
        for (int c2 = 0; c2 < 16; ++c2) buf[pb2 + 8 * c2 + (c2 >> 1)] = x[c2];
    }
    __syncthreads();
    // mid: dft8 fwd + elementwise *K + dft8 inv, all in registers
    {
        const float4* kf4 = g_kf4 + (size_t)h * (FFT_N / 2);
        const int pb3 = 17 * t;
#pragma unroll
        for (int gi = 0; gi < 2; ++gi) {
            f2 x[8];
#pragma unroll
            for (int l = 0; l < 8; ++l) x[l] = buf[pb3 + 8 * gi + l];
            dft8<-1>(x);
#pragma unroll
            for (int q = 0; q < 4; ++q) {
                float4 kk = kf4[(4 * gi + q) * 128 + t];
                x[2 * q]     = cmul(x[2 * q],     (f2){kk.x, kk.y});
                x[2 * q + 1] = cmul(x[2 * q + 1], (f2){kk.z, kk.w});
            }
            dft8<+1>(x);
#pragma unroll
            for (int l = 0; l < 8; ++l) buf[pb3 + 8 * gi + l] = x[l];
        }
    }
    __syncthreads();
    // inv s2 (adjoint: conj twiddle, then inverse butterfly; in-place)
    {
        f2 x[16];
#pragma unroll
        for (int c2 = 0; c2 < 16; ++c2) x[c2] = buf[pb2 + 8 * c2 + (c2 >> 1)];
        tw_apply16<1>(x, ws);
        dft16<+1>(x);
#pragma unroll
        for (int j = 0; j < 16; ++j) buf[pb2 + 8 * j + (j >> 1)] = x[j];
    }
    __syncthreads();
    // inv s1 + epilogue (only low 8 outputs needed)
    {
        f2 x[16];
#pragma unroll
        for (int c = 0; c < 16; ++c) x[c] = buf[pb1 + 136 * c];
        tw_apply16<1>(x, w1);
        f2 y[8];
        dft16_inv_low8(x, y);
        const float Dh = D[h];
        const float invN = 1.0f / (float)FFT_N;
        float* o0row = out + row0 * SEQ_L;
        float* o1row = out + row1 * SEQ_L;
#pragma unroll
        for (int j = 0; j < 8; ++j) {
            f2 o = y[j] * invN + uz[j] * Dh;   // packed epilogue
            o0row[t + 128 * j] = o.x;
            o1row[t + 128 * j] = o.y;
        }
    }
}

extern "C" void kernel_launch(void* const* d_in, const int* in_sizes, int n_in,
                              void* d_out, int out_size, void* d_ws, size_t ws_size,
                              hipStream_t stream) {
    const float* u = (const float*)d_in[0];
    const float* k = (const float*)d_in[1];
    const float* D = (const float*)d_in[2];
    float* out = (float*)d_out;

    kfft_kernel<<<NH, NT, 0, stream>>>(k);
    conv_pair_kernel<<<NB * NH / 2, NT, 0, stream>>>(u, D, out);
}